// Round 20
// baseline (45.287 us; speedup 1.0000x reference)
//
#include <hip/hip_runtime.h>
#include <hip/hip_bf16.h>
#include <math.h>

#define NEG_SLOPE 0.2f
#define LN_EPS 1e-5f

constexpr int B = 64, A = 256, L = 1024, D = 128;

typedef float f32x4 __attribute__((ext_vector_type(4)));
typedef float f32x16 __attribute__((ext_vector_type(16)));
typedef short bf16x8 __attribute__((ext_vector_type(8)));

__device__ __forceinline__ ushort f2bf(float x) {
    __hip_bfloat16 h = __float2bfloat16(x);
    return *reinterpret_cast<ushort*>(&h);
}
__device__ __forceinline__ float bf2f(ushort x) {
    unsigned u = ((unsigned)x) << 16;
    return __uint_as_float(u);
}
__device__ __forceinline__ void gl_lds16(const void* g, void* l) {
    __builtin_amdgcn_global_load_lds(
        (const __attribute__((address_space(1))) unsigned int*)g,
        (__attribute__((address_space(3))) unsigned int*)l, 16, 0, 0);
}

// ---------------------------------------------------------------------------
// K1 "prep" (R11-verified): u = W_mol@w_am, v = W_nb@w_aa,
// c0 = b_mol.w_am + b_al, c1 = b_nb.w_aa, WB[e][d] = bf16(W_nb[d][e]).
// ---------------------------------------------------------------------------
__global__ void prep_kernel(const float* __restrict__ Wmol, const float* __restrict__ bmol,
                            const float* __restrict__ wam, const float* __restrict__ bal,
                            const float* __restrict__ Wnb, const float* __restrict__ bnb,
                            const float* __restrict__ waa,
                            float* __restrict__ u, float* __restrict__ v,
                            float* __restrict__ c0, float* __restrict__ c1,
                            ushort* __restrict__ WB) {
    __shared__ float redU[2], redV[2], redC0[2], redC1[2];
    const int i = blockIdx.x, e = threadIdx.x;
    const int lane = e & 63, wv = e >> 6;
    float wnb_ie = Wnb[i * D + e];
    WB[e * D + i] = f2bf(wnb_ie);
    float pu = Wmol[i * D + e] * wam[e];
    float pv = wnb_ie * waa[e];
    float q0 = (i == 0) ? bmol[e] * wam[e] : 0.f;
    float q1 = (i == 0) ? bnb[e] * waa[e] : 0.f;
    #pragma unroll
    for (int o = 1; o < 64; o <<= 1) {
        pu += __shfl_xor(pu, o); pv += __shfl_xor(pv, o);
        q0 += __shfl_xor(q0, o); q1 += __shfl_xor(q1, o);
    }
    if (lane == 0) { redU[wv] = pu; redV[wv] = pv; redC0[wv] = q0; redC1[wv] = q1; }
    __syncthreads();
    if (e == 0) {
        u[i] = redU[0] + redU[1];
        v[i] = redV[0] + redV[1];
        if (i == 0) { c0[0] = redC0[0] + redC0[1] + bal[0];
                      c1[0] = redC1[0] + redC1[1]; }
    }
}

// ---------------------------------------------------------------------------
// K2 "pre2" (R19-verified): 512 smol blocks + 1024 gl_lds-staged trans blocks.
// ---------------------------------------------------------------------------
__global__ __launch_bounds__(256) void pre2_kernel(
    const float* __restrict__ molf, const float* __restrict__ atom,
    const float* __restrict__ smask,
    const float* __restrict__ u, const float* __restrict__ v,
    const float* __restrict__ c0p, const float* __restrict__ c1p,
    float* __restrict__ smolG, ushort* __restrict__ atomT,
    float* __restrict__ sM) {
    __shared__ __align__(16) float Lf[64 * 128];   // 32 KB fp32 tile (swizzled)
    const int bid = blockIdx.x;
    const int tid = threadIdx.x;

    if (bid < 512) {
        const int r = tid >> 3, q = tid & 7;
        const int row = bid * 32 + r;
        const float* xp = molf + (size_t)row * D + q * 16;
        float p = 0.f;
        #pragma unroll
        for (int k = 0; k < 4; ++k) {
            float4 xv = *(const float4*)&xp[k * 4];
            float4 uv = *(const float4*)&u[q * 16 + k * 4];
            p += xv.x * uv.x + xv.y * uv.y + xv.z * uv.z + xv.w * uv.w;
        }
        p += __shfl_xor(p, 1); p += __shfl_xor(p, 2); p += __shfl_xor(p, 4);
        if (q == 0) smolG[row] = p + c0p[0];
        return;
    }

    const int cc = bid - 512;
    const int x = cc & 7, j = cc >> 3;
    const int b = x + 8 * (j & 7);
    const int l0 = (j >> 3) * 64;
    const int w = tid >> 6, lane = tid & 63;
    const float c1 = c1p[0];

    {
        const float* abase = atom + ((size_t)b * L + l0) * D;
        #pragma unroll
        for (int q = 0; q < 8; ++q) {
            const int r0 = w * 16 + q * 2;
            const int r = r0 + (lane >> 5);
            const float* g = abase + (size_t)r * D + (((lane & 31) ^ (r & 31)) << 2);
            gl_lds16(g, (char*)Lf + r0 * 512);
        }
    }
    __syncthreads();

    {
        const int l = tid >> 2, q = tid & 3;
        float p = 0.f;
        #pragma unroll
        for (int k = 0; k < 8; ++k) {
            const int pc = (q * 8 + k) ^ (l & 31);
            float4 xv = *(const float4*)((const char*)Lf + l * 512 + pc * 16);
            float4 vv = *(const float4*)&v[q * 32 + k * 4];
            p += xv.x * vv.x + xv.y * vv.y + xv.z * vv.z + xv.w * vv.w;
        }
        p += __shfl_xor(p, 1); p += __shfl_xor(p, 2);
        if (q == 0) {
            float msk = smask[(size_t)b * L + l0 + l];
            sM[(size_t)b * L + l0 + l] = (msk > -0.5f) ? (p + c1) : -1e30f;
        }
    }

    {
        const int d = tid >> 1, h = tid & 1;
        const size_t obase = ((size_t)(b * 128 + d) << 10) + l0 + h * 32;
        #pragma unroll
        for (int g4i = 0; g4i < 4; ++g4i) {
            alignas(16) ushort tmp[8];
            #pragma unroll
            for (int m = 0; m < 8; ++m) {
                const int row = h * 32 + g4i * 8 + m;
                const int pc = (d >> 2) ^ (row & 31);
                float val = *(const float*)((const char*)Lf + row * 512
                                            + pc * 16 + (d & 3) * 4);
                tmp[m] = f2bf(val);
            }
            *(int4*)&atomT[obase + g4i * 8] = *(int4*)tmp;
        }
    }
}

// ---------------------------------------------------------------------------
// K3 "pvr": 512 blocks (b, aq = 32 a-rows), 4 waves, 2 blocks/CU.
// Wave w owns d-slice [32w,32w+32) over FULL L: 8 x 32 KB atomT tiles
// ([128 d][128 l] bf16, chunk-XOR), dbuf gl_lds (each wave stages and reads
// only its own 32 rows). P-frag built redundantly per wave (cheap, hides
// staging). acc f32x16 = complete ctx[32a][32d] -> NO cross-wave combine,
// no PP: TT scatter + ctx = T.W MFMA + LN epilogue (reduce-verified) in-block.
// ---------------------------------------------------------------------------
__global__ __launch_bounds__(256, 2) void pvr_kernel(
    const ushort* __restrict__ atomT, const float* __restrict__ sM_g,
    const float* __restrict__ smolG, const float* __restrict__ amask,
    const ushort* __restrict__ WB, const float* __restrict__ bnb,
    const float* __restrict__ gamma, const float* __restrict__ beta,
    float* __restrict__ out) {
    __shared__ __align__(16) char arena[2][32768];   // Ta dbuf [128][128] bf16
    __shared__ __align__(16) ushort eT[1024], fT[1024];
    __shared__ float psums[32];
    __shared__ float gbL[256];
    __shared__ float lnP[4][2][16][2];

    const int bid = blockIdx.x;
    const int x = bid & 7, j = bid >> 3;
    const int b = x + 8 * (j & 7);                   // XCD co-located w/ pre2
    const int aq = j >> 3;
    const int tid = threadIdx.x;
    const int w = tid >> 6, lane = tid & 63;
    const int al = lane & 31, hi = lane >> 5;
    const int la = lane & 15, kg = lane >> 4;
    const int xo = la & 7;

    const ushort* atomTb = atomT + (size_t)b * D * L;

#define STAGE(BUF_, T_)                                                        \
    {                                                                          \
        _Pragma("unroll")                                                      \
        for (int q_ = 0; q_ < 8; ++q_) {                                       \
            const int r0_ = w * 32 + q_ * 4;                                   \
            const int r_ = r0_ + (lane >> 4);                                  \
            const ushort* g_ = atomTb + (size_t)r_ * L + (T_) * 128            \
                               + (((lane & 15) ^ (r_ & 15)) << 3);             \
            gl_lds16(g_, arena[BUF_] + r0_ * 256);                             \
        }                                                                      \
    }

    STAGE(0, 0)

    if (tid < 32)      ((float4*)gbL)[tid] = ((const float4*)gamma)[tid];
    else if (tid < 64) ((float4*)gbL)[tid] = ((const float4*)beta)[tid - 32];
    {   // full-L softmax tables (256 thr x 4)
        const int i4 = tid * 4;
        float4 sa = *(const float4*)&sM_g[(size_t)b * L + i4];
        eT[i4 + 0] = f2bf(__expf(sa.x)); eT[i4 + 1] = f2bf(__expf(sa.y));
        eT[i4 + 2] = f2bf(__expf(sa.z)); eT[i4 + 3] = f2bf(__expf(sa.w));
        fT[i4 + 0] = f2bf(__expf(NEG_SLOPE * sa.x));
        fT[i4 + 1] = f2bf(__expf(NEG_SLOPE * sa.y));
        fT[i4 + 2] = f2bf(__expf(NEG_SLOPE * sa.z));
        fT[i4 + 3] = f2bf(__expf(NEG_SLOPE * sa.w));
    }
    const float smv = smolG[(size_t)b * A + aq * 32 + al];
    const float ea = __expf(smv), fa = __expf(NEG_SLOPE * smv);
    __syncthreads();   // tile 0 staged + tables ready

    f32x16 acc = {};
    float psum = 0.f;

#define COMPUTE(BUF_, T_)                                                      \
    {                                                                          \
        _Pragma("unroll")                                                      \
        for (int c_ = 0; c_ < 8; ++c_) {                                       \
            const int lb_ = (T_) * 128 + c_ * 16 + hi * 8;                     \
            bf16x8 eb = *(const bf16x8*)&eT[lb_];                              \
            bf16x8 fb = *(const bf16x8*)&fT[lb_];                              \
            bf16x8 pf;                                                         \
            _Pragma("unroll")                                                  \
            for (int jj = 0; jj < 8; ++jj) {                                   \
                float p_ = fmaxf(ea * bf2f((ushort)eb[jj]),                    \
                                 fa * bf2f((ushort)fb[jj]));                   \
                psum += p_;                                                    \
                pf[jj] = (short)f2bf(p_);                                      \
            }                                                                  \
            const int ch_ = c_ * 2 + hi;                                       \
            const int row_ = w * 32 + al;                                      \
            bf16x8 af = *(const bf16x8*)(arena[BUF_] + row_ * 256              \
                                         + ((ch_ ^ (row_ & 15)) << 4));        \
            acc = __builtin_amdgcn_mfma_f32_32x32x16_bf16(pf, af, acc, 0, 0, 0); \
        }                                                                      \
    }

    STAGE(1, 1) COMPUTE(0, 0) __syncthreads();
    STAGE(0, 2) COMPUTE(1, 1) __syncthreads();
    STAGE(1, 3) COMPUTE(0, 2) __syncthreads();
    STAGE(0, 4) COMPUTE(1, 3) __syncthreads();
    STAGE(1, 5) COMPUTE(0, 4) __syncthreads();
    STAGE(0, 6) COMPUTE(1, 5) __syncthreads();
    STAGE(1, 7) COMPUTE(0, 6) __syncthreads();
    COMPUTE(1, 7)
#undef COMPUTE
#undef STAGE

    // psum over l (each wave computed full L; lanes al / al+32 are same a)
    psum += __shfl_xor(psum, 32);
    if (w == 0 && lane < 32) psums[al] = psum;

    // TT scatter (reduce-verified pattern): wave w writes d = w*32 + al
    {
        char* TT = arena[0];   // dead (last compute read arena[1])
        const int d = w * 32 + al;
        const int ccd = d >> 3;
        #pragma unroll
        for (int rq = 0; rq < 4; ++rq)
            #pragma unroll
            for (int e = 0; e < 4; ++e) {
                const int arow = e + 8 * rq + 4 * hi;
                *(ushort*)(TT + arow * 256 + ((ccd ^ (arow & 7)) << 4)
                           + (d & 7) * 2) = f2bf(acc[rq * 4 + e]);
            }
    }
    __syncthreads();

    // ---- epilogue (reduce-verified): ctx = T.W MFMA + scale + LN -> out
    bf16x8 wb0[4], wb1[4];
    {
        const ushort* wr0 = WB + (size_t)((2 * w) * 16 + la) * D + kg * 8;
        const ushort* wr1 = WB + (size_t)((2 * w + 1) * 16 + la) * D + kg * 8;
        #pragma unroll
        for (int ks = 0; ks < 4; ++ks) {
            wb0[ks] = *(const bf16x8*)&wr0[ks * 32];
            wb1[ks] = *(const bf16x8*)&wr1[ks * 32];
        }
    }
    float4 bias0 = *(const float4*)&bnb[w * 32 + kg * 4];
    float4 bias1 = *(const float4*)&bnb[w * 32 + 16 + kg * 4];
    const int aG0 = aq * 32;
    const float amA = amask[(size_t)b * A + aG0 + la];
    const float amB = amask[(size_t)b * A + aG0 + 16 + la];
    const float psA = psums[la];
    const float psB = psums[la + 16];

    const char* TTc = arena[0];
#define LDT(ROW_, KS_) (*(const bf16x8*)(TTc + (ROW_) * 256 + \
                         ((((KS_) * 4 + kg) ^ xo) << 4)))
    f32x4 cA0 = {}, cA1 = {}, cB0 = {}, cB1 = {};
    #pragma unroll
    for (int ks = 0; ks < 4; ++ks) {
        bf16x8 tA = LDT(la, ks);
        bf16x8 tB = LDT(la + 16, ks);
        cA0 = __builtin_amdgcn_mfma_f32_16x16x32_bf16(wb0[ks], tA, cA0, 0, 0, 0);
        cA1 = __builtin_amdgcn_mfma_f32_16x16x32_bf16(wb1[ks], tA, cA1, 0, 0, 0);
        cB0 = __builtin_amdgcn_mfma_f32_16x16x32_bf16(wb0[ks], tB, cB0, 0, 0, 0);
        cB1 = __builtin_amdgcn_mfma_f32_16x16x32_bf16(wb1[ks], tB, cB1, 0, 0, 0);
    }
#undef LDT

    const float scA = amA / psA, scB = amB / psB;
    float xA[8], xB[8];
    float s1A = 0.f, s2A = 0.f, s1B = 0.f, s2B = 0.f;
    const float* bp0 = (const float*)&bias0;
    const float* bp1 = (const float*)&bias1;
    #pragma unroll
    for (int r = 0; r < 4; ++r) {
        xA[r]     = cA0[r] * scA + amA * bp0[r];
        xA[4 + r] = cA1[r] * scA + amA * bp1[r];
        xB[r]     = cB0[r] * scB + amB * bp0[r];
        xB[4 + r] = cB1[r] * scB + amB * bp1[r];
        s1A += xA[r] + xA[4 + r]; s2A += xA[r] * xA[r] + xA[4 + r] * xA[4 + r];
        s1B += xB[r] + xB[4 + r]; s2B += xB[r] * xB[r] + xB[4 + r] * xB[4 + r];
    }
    s1A += __shfl_xor(s1A, 16); s1A += __shfl_xor(s1A, 32);
    s2A += __shfl_xor(s2A, 16); s2A += __shfl_xor(s2A, 32);
    s1B += __shfl_xor(s1B, 16); s1B += __shfl_xor(s1B, 32);
    s2B += __shfl_xor(s2B, 16); s2B += __shfl_xor(s2B, 32);
    if (lane < 16) {
        lnP[w][0][la][0] = s1A; lnP[w][0][la][1] = s2A;
        lnP[w][1][la][0] = s1B; lnP[w][1][la][1] = s2B;
    }
    __syncthreads();
    const float S1A = lnP[0][0][la][0] + lnP[1][0][la][0] + lnP[2][0][la][0] + lnP[3][0][la][0];
    const float S2A = lnP[0][0][la][1] + lnP[1][0][la][1] + lnP[2][0][la][1] + lnP[3][0][la][1];
    const float S1B = lnP[0][1][la][0] + lnP[1][1][la][0] + lnP[2][1][la][0] + lnP[3][1][la][0];
    const float S2B = lnP[0][1][la][1] + lnP[1][1][la][1] + lnP[2][1][la][1] + lnP[3][1][la][1];
    const float muA = S1A * (1.f / 128.f);
    const float rsA = rsqrtf(S2A * (1.f / 128.f) - muA * muA + LN_EPS);
    const float muB = S1B * (1.f / 128.f);
    const float rsB = rsqrtf(S2B * (1.f / 128.f) - muB * muB + LN_EPS);
    const size_t oA = ((size_t)b * A + aG0 + la) * D;
    const size_t oB = ((size_t)b * A + aG0 + 16 + la) * D;
    #pragma unroll
    for (int t = 0; t < 2; ++t) {
        const int e0 = w * 32 + t * 16 + kg * 4;
        float4 g4 = *(float4*)&gbL[e0];
        float4 b4 = *(float4*)&gbL[128 + e0];
        float4 ovA, ovB;
        const float* xpA = &xA[t * 4];
        const float* xpB = &xB[t * 4];
        ((float*)&ovA)[0] = (xpA[0] - muA) * rsA * g4.x + b4.x;
        ((float*)&ovA)[1] = (xpA[1] - muA) * rsA * g4.y + b4.y;
        ((float*)&ovA)[2] = (xpA[2] - muA) * rsA * g4.z + b4.z;
        ((float*)&ovA)[3] = (xpA[3] - muA) * rsA * g4.w + b4.w;
        ((float*)&ovB)[0] = (xpB[0] - muB) * rsB * g4.x + b4.x;
        ((float*)&ovB)[1] = (xpB[1] - muB) * rsB * g4.y + b4.y;
        ((float*)&ovB)[2] = (xpB[2] - muB) * rsB * g4.z + b4.z;
        ((float*)&ovB)[3] = (xpB[3] - muB) * rsB * g4.w + b4.w;
        *(float4*)&out[oA + e0] = ovA;
        *(float4*)&out[oB + e0] = ovB;
    }
}

// ---------------------------------------------------------------------------
extern "C" void kernel_launch(void* const* d_in, const int* in_sizes, int n_in,
                              void* d_out, int out_size, void* d_ws, size_t ws_size,
                              hipStream_t stream) {
    const float* molf  = (const float*)d_in[0];
    const float* atomf = (const float*)d_in[1];
    const float* amask = (const float*)d_in[2];
    const float* smask = (const float*)d_in[3];
    const float* W_mol = (const float*)d_in[4];
    const float* b_mol = (const float*)d_in[5];
    const float* W_nb  = (const float*)d_in[6];
    const float* b_nb  = (const float*)d_in[7];
    const float* w_am  = (const float*)d_in[8];
    const float* w_aa  = (const float*)d_in[9];
    const float* b_al  = (const float*)d_in[10];
    const float* gamma = (const float*)d_in[11];
    const float* beta  = (const float*)d_in[12];
    float* out = (float*)d_out;

    // ws: atomT bf16 [B*D*L] | sM [B*L] | smol [B*A] | u,v [D] | c0,c1 | WB
    ushort* atomT = (ushort*)d_ws;
    float* sM     = (float*)(atomT + (size_t)B * D * L);
    float* smolG  = sM + (size_t)B * L;
    float* u_ws   = smolG + (size_t)B * A;
    float* v_ws   = u_ws + D;
    float* c0_ws  = v_ws + D;
    float* c1_ws  = c0_ws + 1;
    ushort* WB    = (ushort*)(c1_ws + 1);

    prep_kernel<<<128, 128, 0, stream>>>(W_mol, b_mol, w_am, b_al, W_nb, b_nb,
                                         w_aa, u_ws, v_ws, c0_ws, c1_ws, WB);
    pre2_kernel<<<512 + 1024, 256, 0, stream>>>(molf, atomf, smask, u_ws, v_ws,
                                                c0_ws, c1_ws, smolG, atomT, sM);
    pvr_kernel<<<512, 256, 0, stream>>>(atomT, sM, smolG, amask, WB, b_nb,
                                        gamma, beta, out);
}

// Round 21
// 38.496 us; speedup vs baseline: 1.1764x; 1.1764x over previous
//
#include <hip/hip_runtime.h>
#include <hip/hip_bf16.h>
#include <math.h>

#define NEG_SLOPE 0.2f
#define LN_EPS 1e-5f

constexpr int B = 64, A = 256, L = 1024, D = 128;

typedef float f32x4 __attribute__((ext_vector_type(4)));
typedef float f32x16 __attribute__((ext_vector_type(16)));
typedef short bf16x8 __attribute__((ext_vector_type(8)));

__device__ __forceinline__ ushort f2bf(float x) {
    __hip_bfloat16 h = __float2bfloat16(x);
    return *reinterpret_cast<ushort*>(&h);
}
__device__ __forceinline__ float bf2f(ushort x) {
    unsigned u = ((unsigned)x) << 16;
    return __uint_as_float(u);
}

// ---------------------------------------------------------------------------
// K1 "prep" (R11/R17-verified): u = W_mol@w_am, v = W_nb@w_aa,
// c0 = b_mol.w_am + b_al, c1 = b_nb.w_aa, WB[e][d] = bf16(W_nb[d][e]).
// ---------------------------------------------------------------------------
__global__ void prep_kernel(const float* __restrict__ Wmol, const float* __restrict__ bmol,
                            const float* __restrict__ wam, const float* __restrict__ bal,
                            const float* __restrict__ Wnb, const float* __restrict__ bnb,
                            const float* __restrict__ waa,
                            float* __restrict__ u, float* __restrict__ v,
                            float* __restrict__ c0, float* __restrict__ c1,
                            ushort* __restrict__ WB) {
    __shared__ float redU[2], redV[2], redC0[2], redC1[2];
    const int i = blockIdx.x, e = threadIdx.x;
    const int lane = e & 63, wv = e >> 6;
    float wnb_ie = Wnb[i * D + e];
    WB[e * D + i] = f2bf(wnb_ie);
    float pu = Wmol[i * D + e] * wam[e];
    float pv = wnb_ie * waa[e];
    float q0 = (i == 0) ? bmol[e] * wam[e] : 0.f;
    float q1 = (i == 0) ? bnb[e] * waa[e] : 0.f;
    #pragma unroll
    for (int o = 1; o < 64; o <<= 1) {
        pu += __shfl_xor(pu, o); pv += __shfl_xor(pv, o);
        q0 += __shfl_xor(q0, o); q1 += __shfl_xor(q1, o);
    }
    if (lane == 0) { redU[wv] = pu; redV[wv] = pv; redC0[wv] = q0; redC1[wv] = q1; }
    __syncthreads();
    if (e == 0) {
        u[i] = redU[0] + redU[1];
        v[i] = redV[0] + redV[1];
        if (i == 0) { c0[0] = redC0[0] + redC0[1] + bal[0];
                      c1[0] = redC1[0] + redC1[1]; }
    }
}

// ---------------------------------------------------------------------------
// K2 "pv" (R17-verified math, + software-pipelined chunk loop): 512 blocks
// (b, lq, ah), 256 thr, 2 blocks/CU. Inline s_mol; per 32-l chunk: raw atom
// fp32 -> dot/tables -> bf16 bounce -> transposed swizzled Ta[128 d][256 l];
// chunk c+1 loads issued BEFORE chunk c's barriers (latency hidden).
// Then MFMA + psum + bf16 PP partials.
// ---------------------------------------------------------------------------
__global__ __launch_bounds__(256, 2) void pv_kernel(
    const float* __restrict__ molf, const float* __restrict__ atom,
    const float* __restrict__ smask,
    const float* __restrict__ u, const float* __restrict__ v,
    const float* __restrict__ c0p, const float* __restrict__ c1p,
    uint2* __restrict__ PP, float* __restrict__ psumP) {
    __shared__ __align__(16) ushort Ta[128][256];   // 64 KB swizzled [d][l]
    __shared__ __align__(16) ushort Ls[32][132];    // 8.25 KB natural bounce
    __shared__ float uL[128], vL[128], smL[128];
    __shared__ ushort eT[256], fT[256];

    const int bid = blockIdx.x;
    const int x = bid & 7, j = bid >> 3;
    const int b = x + 8 * (j & 7);
    const int rest = j >> 3;
    const int lq = rest >> 1, ah = rest & 1;
    const int tid = threadIdx.x;
    const int w = tid >> 6, lane = tid & 63;
    const int al = lane & 31, hi = lane >> 5;

    const int lr = tid >> 3, q = tid & 7;           // chunk-load mapping
    float4 x0, x1, x2, x3, y0, y1, y2, y3;

#define LOADC(C_, A_, B_, C2_, D_)                                             \
    {                                                                          \
        const int l_ = lq * 256 + (C_) * 32 + lr;                              \
        const float* ap_ = atom + ((size_t)b * L + l_) * D + q * 16;           \
        A_  = *(const float4*)&ap_[0];                                         \
        B_  = *(const float4*)&ap_[4];                                         \
        C2_ = *(const float4*)&ap_[8];                                         \
        D_  = *(const float4*)&ap_[12];                                        \
    }

    LOADC(0, x0, x1, x2, x3)   // chunk-0 loads fly under uL/vL + s_mol

    if (tid < 128) { uL[tid] = u[tid]; vL[tid] = v[tid]; }
    __syncthreads();

    // ---- phase 0: s_mol slice (rows ah*128 .. +128), 2 threads per row
    {
        const int r = tid >> 1, h = tid & 1;
        const float* xp = molf + ((size_t)b * A + ah * 128 + r) * D + h * 64;
        float p = 0.f;
        #pragma unroll
        for (int k = 0; k < 16; ++k) {
            float4 xv = *(const float4*)&xp[k * 4];
            float4 uv = *(const float4*)&uL[h * 64 + k * 4];
            p += xv.x * uv.x + xv.y * uv.y + xv.z * uv.z + xv.w * uv.w;
        }
        p += __shfl_xor(p, 1);
        if (h == 0) smL[r] = p + c0p[0];
    }

    const float c1 = c1p[0];

#define PROC(C_, A_, B_, C2_, D_)                                              \
    {                                                                          \
        const float* vp_ = &vL[q * 16];                                        \
        float dot = A_.x * vp_[0] + A_.y * vp_[1] + A_.z * vp_[2]              \
                  + A_.w * vp_[3] + B_.x * vp_[4] + B_.y * vp_[5]              \
                  + B_.z * vp_[6] + B_.w * vp_[7] + C2_.x * vp_[8]             \
                  + C2_.y * vp_[9] + C2_.z * vp_[10] + C2_.w * vp_[11]         \
                  + D_.x * vp_[12] + D_.y * vp_[13] + D_.z * vp_[14]           \
                  + D_.w * vp_[15];                                            \
        dot += __shfl_xor(dot, 1);                                             \
        dot += __shfl_xor(dot, 2);                                             \
        dot += __shfl_xor(dot, 4);                                             \
        union { ushort us[4]; uint2 u2; } pk_;                                 \
        pk_.us[0] = f2bf(A_.x); pk_.us[1] = f2bf(A_.y);                        \
        pk_.us[2] = f2bf(A_.z); pk_.us[3] = f2bf(A_.w);                        \
        *(uint2*)&Ls[lr][q * 16] = pk_.u2;                                     \
        pk_.us[0] = f2bf(B_.x); pk_.us[1] = f2bf(B_.y);                        \
        pk_.us[2] = f2bf(B_.z); pk_.us[3] = f2bf(B_.w);                        \
        *(uint2*)&Ls[lr][q * 16 + 4] = pk_.u2;                                 \
        pk_.us[0] = f2bf(C2_.x); pk_.us[1] = f2bf(C2_.y);                      \
        pk_.us[2] = f2bf(C2_.z); pk_.us[3] = f2bf(C2_.w);                      \
        *(uint2*)&Ls[lr][q * 16 + 8] = pk_.u2;                                 \
        pk_.us[0] = f2bf(D_.x); pk_.us[1] = f2bf(D_.y);                        \
        pk_.us[2] = f2bf(D_.z); pk_.us[3] = f2bf(D_.w);                        \
        *(uint2*)&Ls[lr][q * 16 + 12] = pk_.u2;                                \
        if (q == 0) {                                                          \
            float msk = smask[(size_t)b * L + lq * 256 + (C_) * 32 + lr];      \
            float s = (msk > -0.5f) ? (dot + c1) : -1e30f;                     \
            eT[(C_) * 32 + lr] = f2bf(__expf(s));                              \
            fT[(C_) * 32 + lr] = f2bf(__expf(NEG_SLOPE * s));                  \
        }                                                                      \
    }

#define TRANS(C_)                                                              \
    {                                                                          \
        const int d_ = tid >> 1, h_ = tid & 1;                                 \
        _Pragma("unroll")                                                      \
        for (int hh_ = 0; hh_ < 2; ++hh_) {                                    \
            alignas(16) ushort tmp_[8];                                        \
            _Pragma("unroll")                                                  \
            for (int m_ = 0; m_ < 8; ++m_)                                     \
                tmp_[m_] = Ls[h_ * 16 + hh_ * 8 + m_][d_];                     \
            const int ch_ = (C_) * 4 + h_ * 2 + hh_;                           \
            *(int4*)((char*)&Ta[0][0] + d_ * 512 + ((ch_ ^ (d_ & 15)) << 4)) = \
                *(int4*)tmp_;                                                  \
        }                                                                      \
    }

    // ---- pipelined chunk loop: loads for c+1 issue before c's barriers
    PROC(0, x0, x1, x2, x3) LOADC(1, y0, y1, y2, y3)
    __syncthreads(); TRANS(0) __syncthreads();
    PROC(1, y0, y1, y2, y3) LOADC(2, x0, x1, x2, x3)
    __syncthreads(); TRANS(1) __syncthreads();
    PROC(2, x0, x1, x2, x3) LOADC(3, y0, y1, y2, y3)
    __syncthreads(); TRANS(2) __syncthreads();
    PROC(3, y0, y1, y2, y3) LOADC(4, x0, x1, x2, x3)
    __syncthreads(); TRANS(3) __syncthreads();
    PROC(4, x0, x1, x2, x3) LOADC(5, y0, y1, y2, y3)
    __syncthreads(); TRANS(4) __syncthreads();
    PROC(5, y0, y1, y2, y3) LOADC(6, x0, x1, x2, x3)
    __syncthreads(); TRANS(5) __syncthreads();
    PROC(6, x0, x1, x2, x3) LOADC(7, y0, y1, y2, y3)
    __syncthreads(); TRANS(6) __syncthreads();
    PROC(7, y0, y1, y2, y3)
    __syncthreads(); TRANS(7) __syncthreads();
#undef LOADC
#undef PROC
#undef TRANS

    // ---- MFMA phase (R11/R17-verified body)
    const int aG = ah * 128 + w * 32 + al;
    const float smv = smL[w * 32 + al];
    const float ea = __expf(smv), fa = __expf(NEG_SLOPE * smv);
    f32x16 acc[4] = {};
    float psum = 0.f;
    #pragma unroll 4
    for (int c = 0; c < 16; ++c) {
        const int lb = c * 16 + hi * 8;
        bf16x8 eb = *(const bf16x8*)&eT[lb];
        bf16x8 fb = *(const bf16x8*)&fT[lb];
        bf16x8 pf;
        #pragma unroll
        for (int jj = 0; jj < 8; ++jj) {
            float p_ = fmaxf(ea * bf2f((ushort)eb[jj]), fa * bf2f((ushort)fb[jj]));
            psum += p_;
            pf[jj] = (short)f2bf(p_);
        }
        const int ch = c * 2 + hi;
        #pragma unroll
        for (int dt = 0; dt < 4; ++dt) {
            const int row = dt * 32 + al;
            bf16x8 bf = *(const bf16x8*)((const char*)&Ta[0][0] + row * 512
                                         + ((ch ^ (row & 15)) << 4));
            acc[dt] = __builtin_amdgcn_mfma_f32_32x32x16_bf16(pf, bf, acc[dt], 0, 0, 0);
        }
    }

    psum += __shfl_xor(psum, 32);
    if (hi == 0) psumP[((size_t)b * 4 + lq) * A + aG] = psum;

    const size_t base0 = (((size_t)(b * 4 + lq) * 2 + ah) * 4 + w);
    #pragma unroll
    for (int dt = 0; dt < 4; ++dt) {
        #pragma unroll
        for (int rq = 0; rq < 4; ++rq) {
            union { ushort us[4]; uint2 u2; } pk;
            pk.us[0] = f2bf(acc[dt][rq * 4 + 0]);
            pk.us[1] = f2bf(acc[dt][rq * 4 + 1]);
            pk.us[2] = f2bf(acc[dt][rq * 4 + 2]);
            pk.us[3] = f2bf(acc[dt][rq * 4 + 3]);
            PP[((((base0 * 4 + dt) * 4 + rq) * 2 + hi) * 32) + al] = pk.u2;
        }
    }
}

// ---------------------------------------------------------------------------
// K3 "reduce" (R11/R17-verified): 512 blocks (b, ah, at). Sum 4 lq partials ->
// TT bf16 (chunk-XOR) -> ctx = T.W MFMA + scale + LayerNorm -> out.
// ---------------------------------------------------------------------------
__global__ __launch_bounds__(256) void reduce_kernel(
    const uint2* __restrict__ PP, const float* __restrict__ psumP,
    const float* __restrict__ amask, const ushort* __restrict__ WB,
    const float* __restrict__ bnb,
    const float* __restrict__ gamma, const float* __restrict__ beta,
    float* __restrict__ out) {
    __shared__ __align__(16) ushort TT[32 * 128];
    __shared__ float gbL[256];
    __shared__ float lnP[4][2][16][2];

    const int bid = blockIdx.x;
    const int x = bid & 7, j = bid >> 3;
    const int b = x + 8 * (j & 7);
    const int rest = j >> 3;
    const int ah = rest >> 2, at = rest & 3;
    const int tid = threadIdx.x;
    const int w = tid >> 6, lane = tid & 63;
    const int la = lane & 15, kg = lane >> 4;
    const int xo = la & 7;
    const int aG0 = ah * 128 + at * 32;

    if (tid < 32)      ((float4*)gbL)[tid] = ((const float4*)gamma)[tid];
    else if (tid < 64) ((float4*)gbL)[tid] = ((const float4*)beta)[tid - 32];

    {
        const int rq = tid >> 6, hi2 = (tid >> 5) & 1, al2 = tid & 31;
        float s4[4][4];
        #pragma unroll
        for (int dt = 0; dt < 4; ++dt)
            #pragma unroll
            for (int e = 0; e < 4; ++e) s4[dt][e] = 0.f;
        #pragma unroll
        for (int lq = 0; lq < 4; ++lq) {
            const size_t bb = (((size_t)(b * 4 + lq) * 2 + ah) * 4 + at);
            #pragma unroll
            for (int dt = 0; dt < 4; ++dt) {
                uint2 v = PP[((((bb * 4 + dt) * 4 + rq) * 2 + hi2) * 32) + al2];
                s4[dt][0] += bf2f((ushort)(v.x & 0xffff));
                s4[dt][1] += bf2f((ushort)(v.x >> 16));
                s4[dt][2] += bf2f((ushort)(v.y & 0xffff));
                s4[dt][3] += bf2f((ushort)(v.y >> 16));
            }
        }
        #pragma unroll
        for (int dt = 0; dt < 4; ++dt) {
            const int d = dt * 32 + al2;
            const int cc = d >> 3;
            #pragma unroll
            for (int e = 0; e < 4; ++e) {
                const int arow = e + 8 * rq + 4 * hi2;
                *(ushort*)((char*)TT + arow * 256 + ((cc ^ (arow & 7)) << 4)
                           + (d & 7) * 2) = f2bf(s4[dt][e]);
            }
        }
    }

    bf16x8 wb0[4], wb1[4];
    {
        const ushort* wr0 = WB + (size_t)((2 * w) * 16 + la) * D + kg * 8;
        const ushort* wr1 = WB + (size_t)((2 * w + 1) * 16 + la) * D + kg * 8;
        #pragma unroll
        for (int ks = 0; ks < 4; ++ks) {
            wb0[ks] = *(const bf16x8*)&wr0[ks * 32];
            wb1[ks] = *(const bf16x8*)&wr1[ks * 32];
        }
    }
    float4 bias0 = *(const float4*)&bnb[w * 32 + kg * 4];
    float4 bias1 = *(const float4*)&bnb[w * 32 + 16 + kg * 4];
    const float amA = amask[(size_t)b * A + aG0 + la];
    const float amB = amask[(size_t)b * A + aG0 + 16 + la];
    float psA = 0.f, psB = 0.f;
    #pragma unroll
    for (int lq = 0; lq < 4; ++lq) {
        psA += psumP[((size_t)b * 4 + lq) * A + aG0 + la];
        psB += psumP[((size_t)b * 4 + lq) * A + aG0 + 16 + la];
    }
    __syncthreads();

    const char* TTc = (const char*)TT;
#define LDT(ROW_, KS_) (*(const bf16x8*)(TTc + (ROW_) * 256 + \
                         ((((KS_) * 4 + kg) ^ xo) << 4)))
    f32x4 cA0 = {}, cA1 = {}, cB0 = {}, cB1 = {};
    #pragma unroll
    for (int ks = 0; ks < 4; ++ks) {
        bf16x8 tA = LDT(la, ks);
        bf16x8 tB = LDT(la + 16, ks);
        cA0 = __builtin_amdgcn_mfma_f32_16x16x32_bf16(wb0[ks], tA, cA0, 0, 0, 0);
        cA1 = __builtin_amdgcn_mfma_f32_16x16x32_bf16(wb1[ks], tA, cA1, 0, 0, 0);
        cB0 = __builtin_amdgcn_mfma_f32_16x16x32_bf16(wb0[ks], tB, cB0, 0, 0, 0);
        cB1 = __builtin_amdgcn_mfma_f32_16x16x32_bf16(wb1[ks], tB, cB1, 0, 0, 0);
    }
#undef LDT

    const float scA = amA / psA, scB = amB / psB;
    float xA[8], xB[8];
    float s1A = 0.f, s2A = 0.f, s1B = 0.f, s2B = 0.f;
    const float* bp0 = (const float*)&bias0;
    const float* bp1 = (const float*)&bias1;
    #pragma unroll
    for (int r = 0; r < 4; ++r) {
        xA[r]     = cA0[r] * scA + amA * bp0[r];
        xA[4 + r] = cA1[r] * scA + amA * bp1[r];
        xB[r]     = cB0[r] * scB + amB * bp0[r];
        xB[4 + r] = cB1[r] * scB + amB * bp1[r];
        s1A += xA[r] + xA[4 + r]; s2A += xA[r] * xA[r] + xA[4 + r] * xA[4 + r];
        s1B += xB[r] + xB[4 + r]; s2B += xB[r] * xB[r] + xB[4 + r] * xB[4 + r];
    }
    s1A += __shfl_xor(s1A, 16); s1A += __shfl_xor(s1A, 32);
    s2A += __shfl_xor(s2A, 16); s2A += __shfl_xor(s2A, 32);
    s1B += __shfl_xor(s1B, 16); s1B += __shfl_xor(s1B, 32);
    s2B += __shfl_xor(s2B, 16); s2B += __shfl_xor(s2B, 32);
    if (lane < 16) {
        lnP[w][0][la][0] = s1A; lnP[w][0][la][1] = s2A;
        lnP[w][1][la][0] = s1B; lnP[w][1][la][1] = s2B;
    }
    __syncthreads();
    const float S1A = lnP[0][0][la][0] + lnP[1][0][la][0] + lnP[2][0][la][0] + lnP[3][0][la][0];
    const float S2A = lnP[0][0][la][1] + lnP[1][0][la][1] + lnP[2][0][la][1] + lnP[3][0][la][1];
    const float S1B = lnP[0][1][la][0] + lnP[1][1][la][0] + lnP[2][1][la][0] + lnP[3][1][la][0];
    const float S2B = lnP[0][1][la][1] + lnP[1][1][la][1] + lnP[2][1][la][1] + lnP[3][1][la][1];
    const float muA = S1A * (1.f / 128.f);
    const float rsA = rsqrtf(S2A * (1.f / 128.f) - muA * muA + LN_EPS);
    const float muB = S1B * (1.f / 128.f);
    const float rsB = rsqrtf(S2B * (1.f / 128.f) - muB * muB + LN_EPS);
    const size_t oA = ((size_t)b * A + aG0 + la) * D;
    const size_t oB = ((size_t)b * A + aG0 + 16 + la) * D;
    #pragma unroll
    for (int t = 0; t < 2; ++t) {
        const int e0 = w * 32 + t * 16 + kg * 4;
        float4 g4 = *(float4*)&gbL[e0];
        float4 b4 = *(float4*)&gbL[128 + e0];
        float4 ovA, ovB;
        const float* xpA = &xA[t * 4];
        const float* xpB = &xB[t * 4];
        ((float*)&ovA)[0] = (xpA[0] - muA) * rsA * g4.x + b4.x;
        ((float*)&ovA)[1] = (xpA[1] - muA) * rsA * g4.y + b4.y;
        ((float*)&ovA)[2] = (xpA[2] - muA) * rsA * g4.z + b4.z;
        ((float*)&ovA)[3] = (xpA[3] - muA) * rsA * g4.w + b4.w;
        ((float*)&ovB)[0] = (xpB[0] - muB) * rsB * g4.x + b4.x;
        ((float*)&ovB)[1] = (xpB[1] - muB) * rsB * g4.y + b4.y;
        ((float*)&ovB)[2] = (xpB[2] - muB) * rsB * g4.z + b4.z;
        ((float*)&ovB)[3] = (xpB[3] - muB) * rsB * g4.w + b4.w;
        *(float4*)&out[oA + e0] = ovA;
        *(float4*)&out[oB + e0] = ovB;
    }
}

// ---------------------------------------------------------------------------
extern "C" void kernel_launch(void* const* d_in, const int* in_sizes, int n_in,
                              void* d_out, int out_size, void* d_ws, size_t ws_size,
                              hipStream_t stream) {
    const float* molf  = (const float*)d_in[0];
    const float* atomf = (const float*)d_in[1];
    const float* amask = (const float*)d_in[2];
    const float* smask = (const float*)d_in[3];
    const float* W_mol = (const float*)d_in[4];
    const float* b_mol = (const float*)d_in[5];
    const float* W_nb  = (const float*)d_in[6];
    const float* b_nb  = (const float*)d_in[7];
    const float* w_am  = (const float*)d_in[8];
    const float* w_aa  = (const float*)d_in[9];
    const float* b_al  = (const float*)d_in[10];
    const float* gamma = (const float*)d_in[11];
    const float* beta  = (const float*)d_in[12];
    float* out = (float*)d_out;

    // ws: PP uint2 [B*4*A*D/4] | psumP [B*4*A] | u,v [D] | c0,c1 | WB bf16
    uint2* PP     = (uint2*)d_ws;
    float* psumP  = (float*)(PP + (size_t)B * 4 * A * D / 4);
    float* u_ws   = psumP + (size_t)B * 4 * A;
    float* v_ws   = u_ws + D;
    float* c0_ws  = v_ws + D;
    float* c1_ws  = c0_ws + 1;
    ushort* WB    = (ushort*)(c1_ws + 1);

    prep_kernel<<<128, 128, 0, stream>>>(W_mol, b_mol, w_am, b_al, W_nb, b_nb,
                                         w_aa, u_ws, v_ws, c0_ws, c1_ws, WB);
    pv_kernel<<<512, 256, 0, stream>>>(molf, atomf, smask, u_ws, v_ws,
                                       c0_ws, c1_ws, PP, psumP);
    reduce_kernel<<<512, 256, 0, stream>>>(PP, psumP, amask, WB, b_nb,
                                           gamma, beta, out);
}